// Round 2
// baseline (1148.115 us; speedup 1.0000x reference)
//
#include <hip/hip_runtime.h>
#include <hip/hip_bf16.h>

namespace {
constexpr int NA   = 8;      // agents
constexpr int BT   = 32768;  // B*T tokens
constexpr int NOBS = 64;
constexpr int NACT = 16;
constexpr int IDIM = 80;     // OBS+ACT
constexpr int NH   = 128;
constexpr int NE   = 4;      // heads
constexpr int ND   = 32;     // head dim
constexpr int TOK  = 8;      // tokens per block
constexpr int NTHREADS = 512;
}

__device__ __forceinline__ float lrelu(float x) { return x > 0.0f ? x : 0.01f * x; }

__global__ __launch_bounds__(NTHREADS) void maac_fused(
    const float* __restrict__ g_obs, const float* __restrict__ g_u,
    const float* __restrict__ g_encW, const float* __restrict__ g_encb,
    const float* __restrict__ g_sW,   const float* __restrict__ g_sb,
    const float* __restrict__ g_keyW, const float* __restrict__ g_selW,
    const float* __restrict__ g_valW, const float* __restrict__ g_valb,
    const float* __restrict__ g_cW1,  const float* __restrict__ g_cb1,
    const float* __restrict__ g_cW2,  const float* __restrict__ g_cb2,
    float* __restrict__ g_out)
{
  // LDS layout (manual offsets; s_h1 aliases s_keys, which is dead after attention)
  __shared__ __align__(16) char smem[127232];
  float          (*s_inp )[IDIM][TOK]    = reinterpret_cast<float (*)[IDIM][TOK]>(smem);                     // 20480 B
  __hip_bfloat16 (*s_sa  )[NH][TOK]      = reinterpret_cast<__hip_bfloat16 (*)[NH][TOK]>(smem + 20480);      // 16384
  __hip_bfloat16 (*s_se  )[NH][TOK]      = reinterpret_cast<__hip_bfloat16 (*)[NH][TOK]>(smem + 36864);      // 16384
  __hip_bfloat16 (*s_keys)[NA][ND][TOK]  = reinterpret_cast<__hip_bfloat16 (*)[NA][ND][TOK]>(smem + 53248);  // 16384
  __hip_bfloat16 (*s_vals)[NA][ND][TOK]  = reinterpret_cast<__hip_bfloat16 (*)[NA][ND][TOK]>(smem + 69632);  // 16384
  __hip_bfloat16 (*s_sel )[NA][ND][TOK]  = reinterpret_cast<__hip_bfloat16 (*)[NA][ND][TOK]>(smem + 86016);  // 16384
  __hip_bfloat16 (*s_other)[NH][TOK]     = reinterpret_cast<__hip_bfloat16 (*)[NH][TOK]>(smem + 102400);     // 16384
  __hip_bfloat16 (*s_h1  )[NH][TOK]      = reinterpret_cast<__hip_bfloat16 (*)[NH][TOK]>(smem + 53248);      // alias keys
  float          (*s_w   )[NA][TOK][NA]  = reinterpret_cast<float (*)[NA][TOK][NA]>(smem + 118784);          // 8192 [e][i][t][j]
  int            (*s_idx )[TOK]          = reinterpret_cast<int (*)[TOK]>(smem + 126976);                    // 256

  const int tid = threadIdx.x;
  const int g0  = blockIdx.x * TOK;   // first token (b*T + t) of this block

  // ---------------- Phase 0: stage inputs (obs|u concat), argmax(u) ----------------
  for (int e = tid; e < NA * TOK * IDIM; e += NTHREADS) {
    int a = e / (TOK * IDIM);
    int r = e - a * (TOK * IDIM);
    int t = r / IDIM;
    int k = r - t * IDIM;
    float v;
    if (k < NOBS) v = g_obs[(size_t)(a * BT + g0 + t) * NOBS + k];
    else          v = g_u  [(size_t)(a * BT + g0 + t) * NACT + (k - NOBS)];
    s_inp[a][k][t] = v;
  }
  if (tid < NA * TOK) {
    int aa = tid >> 3, t = tid & 7;
    const float* up = g_u + (size_t)(aa * BT + g0 + t) * NACT;
    int best = 0; float bv = up[0];
    #pragma unroll
    for (int o = 1; o < NACT; ++o) { float v = up[o]; if (v > bv) { bv = v; best = o; } }  // first-max, like jnp.argmax
    s_idx[aa][t] = best;
  }
  __syncthreads();

  const int a  = tid >> 6;   // 64 threads per agent
  const int hh = tid & 63;   // column pair {hh, hh+64}

  // ---------------- Phase 1: sa = lrelu(inp @ enc_W + enc_b) ----------------
  {
    float acc0[TOK], acc1[TOK];
    const float b0 = g_encb[a * NH + hh], b1 = g_encb[a * NH + hh + 64];
    #pragma unroll
    for (int t = 0; t < TOK; ++t) { acc0[t] = b0; acc1[t] = b1; }
    for (int k = 0; k < IDIM; ++k) {
      float w0 = g_encW[(a * IDIM + k) * NH + hh];
      float w1 = g_encW[(a * IDIM + k) * NH + hh + 64];
      #pragma unroll
      for (int t = 0; t < TOK; ++t) {
        float x = s_inp[a][k][t];
        acc0[t] = fmaf(x, w0, acc0[t]);
        acc1[t] = fmaf(x, w1, acc1[t]);
      }
    }
    #pragma unroll
    for (int t = 0; t < TOK; ++t) {
      s_sa[a][hh][t]      = __float2bfloat16(lrelu(acc0[t]));
      s_sa[a][hh + 64][t] = __float2bfloat16(lrelu(acc1[t]));
    }
  }
  // ---------------- Phase 2: se = lrelu(obs @ s_W + s_b) ----------------
  {
    float acc0[TOK], acc1[TOK];
    const float b0 = g_sb[a * NH + hh], b1 = g_sb[a * NH + hh + 64];
    #pragma unroll
    for (int t = 0; t < TOK; ++t) { acc0[t] = b0; acc1[t] = b1; }
    for (int k = 0; k < NOBS; ++k) {
      float w0 = g_sW[(a * NOBS + k) * NH + hh];
      float w1 = g_sW[(a * NOBS + k) * NH + hh + 64];
      #pragma unroll
      for (int t = 0; t < TOK; ++t) {
        float x = s_inp[a][k][t];
        acc0[t] = fmaf(x, w0, acc0[t]);
        acc1[t] = fmaf(x, w1, acc1[t]);
      }
    }
    #pragma unroll
    for (int t = 0; t < TOK; ++t) {
      s_se[a][hh][t]      = __float2bfloat16(lrelu(acc0[t]));
      s_se[a][hh + 64][t] = __float2bfloat16(lrelu(acc1[t]));
    }
  }
  __syncthreads();

  // ---------------- Phase 3: keys/vals (from sa), sel (from se) ----------------
  {
    const int c  = tid & 63;
    const int e0 = c >> 5, d0 = c & 31, e1 = e0 + 2;   // columns c and c+64
    // keys + vals share the sa reads
    float k0[TOK] = {}, k1[TOK] = {}, v0[TOK], v1[TOK];
    const float vb0 = g_valb[e0 * ND + d0], vb1 = g_valb[e1 * ND + d0];
    #pragma unroll
    for (int t = 0; t < TOK; ++t) { v0[t] = vb0; v1[t] = vb1; }
    for (int h = 0; h < NH; ++h) {
      float kw0 = g_keyW[(e0 * NH + h) * ND + d0];
      float kw1 = g_keyW[(e1 * NH + h) * ND + d0];
      float vw0 = g_valW[(e0 * NH + h) * ND + d0];
      float vw1 = g_valW[(e1 * NH + h) * ND + d0];
      #pragma unroll
      for (int t = 0; t < TOK; ++t) {
        float x = __bfloat162float(s_sa[a][h][t]);
        k0[t] = fmaf(x, kw0, k0[t]);
        k1[t] = fmaf(x, kw1, k1[t]);
        v0[t] = fmaf(x, vw0, v0[t]);
        v1[t] = fmaf(x, vw1, v1[t]);
      }
    }
    #pragma unroll
    for (int t = 0; t < TOK; ++t) {
      s_keys[e0][a][d0][t] = __float2bfloat16(k0[t]);
      s_keys[e1][a][d0][t] = __float2bfloat16(k1[t]);
      s_vals[e0][a][d0][t] = __float2bfloat16(lrelu(v0[t]));
      s_vals[e1][a][d0][t] = __float2bfloat16(lrelu(v1[t]));
    }
    float q0[TOK] = {}, q1[TOK] = {};
    for (int h = 0; h < NH; ++h) {
      float sw0 = g_selW[(e0 * NH + h) * ND + d0];
      float sw1 = g_selW[(e1 * NH + h) * ND + d0];
      #pragma unroll
      for (int t = 0; t < TOK; ++t) {
        float x = __bfloat162float(s_se[a][h][t]);
        q0[t] = fmaf(x, sw0, q0[t]);
        q1[t] = fmaf(x, sw1, q1[t]);
      }
    }
    #pragma unroll
    for (int t = 0; t < TOK; ++t) {
      s_sel[e0][a][d0][t] = __float2bfloat16(q0[t]);
      s_sel[e1][a][d0][t] = __float2bfloat16(q1[t]);
    }
  }
  __syncthreads();

  // ---------------- Phase 4: masked softmax over agents j ----------------
  if (tid < NE * NA * TOK) {
    const int e = tid >> 6, i = (tid >> 3) & 7, t = tid & 7;
    float lg[NA];
    #pragma unroll
    for (int j = 0; j < NA; ++j) {
      float acc = 0.0f;
      for (int d = 0; d < ND; ++d)
        acc = fmaf(__bfloat162float(s_sel[e][i][d][t]),
                   __bfloat162float(s_keys[e][j][d][t]), acc);
      lg[j] = acc * 0.17677669529663687f;  // 1/sqrt(32)
    }
    lg[i] = -1e9f;                          // self-exclusion (matches jnp.where then softmax)
    float m = lg[0];
    #pragma unroll
    for (int j = 1; j < NA; ++j) m = fmaxf(m, lg[j]);
    float s = 0.0f;
    #pragma unroll
    for (int j = 0; j < NA; ++j) { float w = __expf(lg[j] - m); lg[j] = w; s += w; }
    float inv = 1.0f / s;
    #pragma unroll
    for (int j = 0; j < NA; ++j) s_w[e][i][t][j] = lg[j] * inv;
  }
  __syncthreads();

  // ---------------- Phase 5: other = w @ vals (head-concat h = e*32+d) ----------------
  {
    const int c  = tid & 63;
    const int e0 = c >> 5, d0 = c & 31, e1 = e0 + 2;
    float o0[TOK] = {}, o1[TOK] = {};
    for (int j = 0; j < NA; ++j) {
      #pragma unroll
      for (int t = 0; t < TOK; ++t) {
        o0[t] = fmaf(s_w[e0][a][t][j], __bfloat162float(s_vals[e0][j][d0][t]), o0[t]);
        o1[t] = fmaf(s_w[e1][a][t][j], __bfloat162float(s_vals[e1][j][d0][t]), o1[t]);
      }
    }
    #pragma unroll
    for (int t = 0; t < TOK; ++t) {
      s_other[a][c][t]      = __float2bfloat16(o0[t]);   // h = e0*32+d0 = c
      s_other[a][c + 64][t] = __float2bfloat16(o1[t]);   // h = e1*32+d0 = c+64
    }
  }
  __syncthreads();

  // ---------------- Phase 6: h1 = lrelu([se|other] @ crit_W1 + b1) ----------------
  {
    float acc0[TOK], acc1[TOK];
    const float b0 = g_cb1[a * NH + hh], b1 = g_cb1[a * NH + hh + 64];
    #pragma unroll
    for (int t = 0; t < TOK; ++t) { acc0[t] = b0; acc1[t] = b1; }
    for (int k = 0; k < NH; ++k) {
      float w0 = g_cW1[(a * 2 * NH + k) * NH + hh];
      float w1 = g_cW1[(a * 2 * NH + k) * NH + hh + 64];
      #pragma unroll
      for (int t = 0; t < TOK; ++t) {
        float x = __bfloat162float(s_se[a][k][t]);
        acc0[t] = fmaf(x, w0, acc0[t]);
        acc1[t] = fmaf(x, w1, acc1[t]);
      }
    }
    for (int k = 0; k < NH; ++k) {
      float w0 = g_cW1[(a * 2 * NH + NH + k) * NH + hh];
      float w1 = g_cW1[(a * 2 * NH + NH + k) * NH + hh + 64];
      #pragma unroll
      for (int t = 0; t < TOK; ++t) {
        float x = __bfloat162float(s_other[a][k][t]);
        acc0[t] = fmaf(x, w0, acc0[t]);
        acc1[t] = fmaf(x, w1, acc1[t]);
      }
    }
    __syncthreads();  // keys (aliased by h1) fully consumed in phase 4; vals consumed in phase 5
    #pragma unroll
    for (int t = 0; t < TOK; ++t) {
      s_h1[a][hh][t]      = __float2bfloat16(lrelu(acc0[t]));
      s_h1[a][hh + 64][t] = __float2bfloat16(lrelu(acc1[t]));
    }
  }
  __syncthreads();

  // ---------------- Phase 7: q = (h1 @ crit_W2 + b2)[idx] ----------------
  if (tid < NA * TOK) {
    const int aa = tid >> 3, t = tid & 7;
    const int o = s_idx[aa][t];
    float acc = g_cb2[aa * NACT + o];
    for (int h = 0; h < NH; ++h)
      acc = fmaf(__bfloat162float(s_h1[aa][h][t]),
                 g_cW2[(aa * NH + h) * NACT + o], acc);
    g_out[(size_t)(aa * BT) + g0 + t] = acc;   // f32 output, per reference dtype
  }
}

extern "C" void kernel_launch(void* const* d_in, const int* in_sizes, int n_in,
                              void* d_out, int out_size, void* d_ws, size_t ws_size,
                              hipStream_t stream) {
  (void)in_sizes; (void)n_in; (void)d_ws; (void)ws_size; (void)out_size;
  const float* obs   = (const float*)d_in[0];
  const float* u     = (const float*)d_in[1];
  const float* encW  = (const float*)d_in[2];
  const float* encb  = (const float*)d_in[3];
  const float* sW    = (const float*)d_in[4];
  const float* sb    = (const float*)d_in[5];
  const float* keyW  = (const float*)d_in[6];
  const float* selW  = (const float*)d_in[7];
  const float* valW  = (const float*)d_in[8];
  const float* valb  = (const float*)d_in[9];
  const float* cW1   = (const float*)d_in[10];
  const float* cb1   = (const float*)d_in[11];
  const float* cW2   = (const float*)d_in[12];
  const float* cb2   = (const float*)d_in[13];

  dim3 grid(BT / TOK);      // 4096 blocks
  dim3 block(NTHREADS);     // 512 threads
  hipLaunchKernelGGL(maac_fused, grid, block, 0, stream,
                     obs, u, encW, encb, sW, sb, keyW, selW, valW, valb,
                     cW1, cb1, cW2, cb2, (float*)d_out);
}

// Round 3
// 408.817 us; speedup vs baseline: 2.8084x; 2.8084x over previous
//
#include <hip/hip_runtime.h>

namespace {
constexpr int NA = 8, BT = 32768, NOBS = 64, NACT = 16, NH = 128;
constexpr int TOK = 16, NTHREADS = 512;
// g_wt table offsets (u16 units)
constexpr int OFF_ENC = 0;        // [8][128n][96k] (k>=80 zero)
constexpr int OFF_S   = 98304;    // [8][128n][64k]
constexpr int OFF_KEY = 163840;   // [128n][128k]  n = e*32+d
constexpr int OFF_SEL = 180224;   // [128n][128k]
constexpr int OFF_VAL = 196608;   // [128n][128k]
constexpr int OFF_C1  = 212992;   // [8][128n][256k]
constexpr int OFF_C2  = 475136;   // [8][16n][128k]
constexpr int WT_TOTAL = 491520;
}

typedef short short8 __attribute__((ext_vector_type(8)));
typedef float f32x4 __attribute__((ext_vector_type(4)));
typedef unsigned short u16;

__device__ u16 g_wt[WT_TOTAL];

__device__ __forceinline__ u16 f2b(float x) {  // RNE f32->bf16
  unsigned b = __float_as_uint(x);
  return (u16)((b + 0x7FFFu + ((b >> 16) & 1u)) >> 16);
}
__device__ __forceinline__ float b2f(u16 h) { return __uint_as_float(((unsigned)h) << 16); }
__device__ __forceinline__ float lrelu(float x) { return x > 0.0f ? x : 0.01f * x; }
__device__ __forceinline__ short8 ld8(const u16* p) { return *reinterpret_cast<const short8*>(p); }
__device__ __forceinline__ short8 pk8(float4 p, float4 q) {
  short8 r;
  r[0] = (short)f2b(p.x); r[1] = (short)f2b(p.y); r[2] = (short)f2b(p.z); r[3] = (short)f2b(p.w);
  r[4] = (short)f2b(q.x); r[5] = (short)f2b(q.y); r[6] = (short)f2b(q.z); r[7] = (short)f2b(q.w);
  return r;
}

// ---------------- Prologue: transpose+cvt all weights into g_wt ----------------
__global__ void maac_wt(const float* __restrict__ encW, const float* __restrict__ sW,
                        const float* __restrict__ keyW, const float* __restrict__ selW,
                        const float* __restrict__ valW, const float* __restrict__ cW1,
                        const float* __restrict__ cW2) {
  for (int i = blockIdx.x * blockDim.x + threadIdx.x; i < WT_TOTAL; i += gridDim.x * blockDim.x) {
    float v; int o = i;
    if (o < OFF_S) {                // enc: [a][n][96] <- encW[a][k][n], zero k>=80
      int a = o / 12288, r = o % 12288, n = r / 96, k = r % 96;
      v = (k < 80) ? encW[a * 10240 + k * 128 + n] : 0.0f;
    } else if (o < OFF_KEY) {       // s: [a][n][64]
      int q = o - OFF_S; int a = q / 8192, r = q % 8192, n = r / 64, k = r % 64;
      v = sW[a * 8192 + k * 128 + n];
    } else if (o < OFF_SEL) {       // key: [n=e*32+d][k=h]
      int q = o - OFF_KEY; int n = q / 128, k = q % 128;
      v = keyW[(n >> 5) * 4096 + k * 32 + (n & 31)];
    } else if (o < OFF_VAL) {
      int q = o - OFF_SEL; int n = q / 128, k = q % 128;
      v = selW[(n >> 5) * 4096 + k * 32 + (n & 31)];
    } else if (o < OFF_C1) {
      int q = o - OFF_VAL; int n = q / 128, k = q % 128;
      v = valW[(n >> 5) * 4096 + k * 32 + (n & 31)];
    } else if (o < OFF_C2) {        // c1: [a][n][256]
      int q = o - OFF_C1; int a = q / 32768, r = q % 32768, n = r / 256, k = r % 256;
      v = cW1[a * 32768 + k * 128 + n];
    } else {                        // c2: [a][n=o][128]
      int q = o - OFF_C2; int a = q / 2048, r = q % 2048, n = r / 128, k = r % 128;
      v = cW2[a * 2048 + k * 16 + n];
    }
    g_wt[i] = f2b(v);
  }
}

// ---------------- Main fused kernel: 16 tokens x 8 agents per block ----------------
// LDS (u16 units): SA[8][16][136]=17408, SE same, BUF1 20480 ([e][8x][16t][40]),
// BUF2 20480 (keys, later other [a][16t][136]), W 4096 ([e][8i][16t][8j])
__global__ __launch_bounds__(NTHREADS) void maac_main(
    const float* __restrict__ g_obs, const float* __restrict__ g_u,
    const float* __restrict__ g_encb, const float* __restrict__ g_sb,
    const float* __restrict__ g_valb, const float* __restrict__ g_cb1,
    const float* __restrict__ g_cb2, float* __restrict__ g_out) {
  __shared__ __align__(16) u16 lds[79872];
  __shared__ int s_idx[128];
  constexpr int SA = 0, SE = 17408, BUF1 = 34816, BUF2 = 55296, SW = 75776;

  const int tid = threadIdx.x;
  const int g0 = blockIdx.x * TOK;
  const int a = tid >> 6, l = tid & 63, lr = l & 15, lg = l >> 4;

  // ---- P0: argmax(u) (first-max) ----
  if (tid < 128) {
    int aa = tid >> 4, t = tid & 15;
    const float* up = g_u + ((size_t)aa * BT + g0 + t) * NACT;
    int best = 0; float bv = up[0];
    #pragma unroll
    for (int o = 1; o < NACT; ++o) { float v = up[o]; if (v > bv) { bv = v; best = o; } }
    s_idx[tid] = best;
  }

  // ---- A-frags for enc/s_enc from global: row = token g0+lr, k = ks*32+lg*8+j ----
  short8 afr0, afr1, afr2;
  {
    const float4* o4 = reinterpret_cast<const float4*>(g_obs + ((size_t)a * BT + g0 + lr) * NOBS);
    afr0 = pk8(o4[lg * 2], o4[lg * 2 + 1]);
    afr1 = pk8(o4[8 + lg * 2], o4[8 + lg * 2 + 1]);
    if (lg < 2) {
      const float4* u4 = reinterpret_cast<const float4*>(g_u + ((size_t)a * BT + g0 + lr) * NACT);
      afr2 = pk8(u4[lg * 2], u4[lg * 2 + 1]);
    } else {
      afr2 = short8{0, 0, 0, 0, 0, 0, 0, 0};
    }
  }

  // ---- P1: sa = lrelu(inp @ encW + encb) -> SA [a][t][136] ----
  {
    const u16* wb = g_wt + OFF_ENC + a * 12288 + lr * 96 + lg * 8;
    #pragma unroll
    for (int nt = 0; nt < 8; ++nt) {
      f32x4 acc = {0.f, 0.f, 0.f, 0.f};
      const u16* wr = wb + nt * (16 * 96);
      acc = __builtin_amdgcn_mfma_f32_16x16x32_bf16(afr0, ld8(wr), acc, 0, 0, 0);
      acc = __builtin_amdgcn_mfma_f32_16x16x32_bf16(afr1, ld8(wr + 32), acc, 0, 0, 0);
      acc = __builtin_amdgcn_mfma_f32_16x16x32_bf16(afr2, ld8(wr + 64), acc, 0, 0, 0);
      float bias = g_encb[a * NH + nt * 16 + lr];
      #pragma unroll
      for (int r = 0; r < 4; ++r)
        lds[SA + (a * 16 + 4 * lg + r) * 136 + nt * 16 + lr] = f2b(lrelu(acc[r] + bias));
    }
  }
  // ---- P2: se = lrelu(obs @ sW + sb) -> SE ----
  {
    const u16* wb = g_wt + OFF_S + a * 8192 + lr * 64 + lg * 8;
    #pragma unroll
    for (int nt = 0; nt < 8; ++nt) {
      f32x4 acc = {0.f, 0.f, 0.f, 0.f};
      const u16* wr = wb + nt * (16 * 64);
      acc = __builtin_amdgcn_mfma_f32_16x16x32_bf16(afr0, ld8(wr), acc, 0, 0, 0);
      acc = __builtin_amdgcn_mfma_f32_16x16x32_bf16(afr1, ld8(wr + 32), acc, 0, 0, 0);
      float bias = g_sb[a * NH + nt * 16 + lr];
      #pragma unroll
      for (int r = 0; r < 4; ++r)
        lds[SE + (a * 16 + 4 * lg + r) * 136 + nt * 16 + lr] = f2b(lrelu(acc[r] + bias));
    }
  }
  __syncthreads();

  // ---- A-frags from LDS (k-contig rows, stride 136) ----
  short8 sefr[4], safr[4];
  #pragma unroll
  for (int ks = 0; ks < 4; ++ks) {
    sefr[ks] = ld8(&lds[SE + (a * 16 + lr) * 136 + ks * 32 + lg * 8]);
    safr[ks] = ld8(&lds[SA + (a * 16 + lr) * 136 + ks * 32 + lg * 8]);
  }

  // ---- P3: sel = se @ selW -> BUF1 [e][i=a][t][40] ; P4: keys = sa @ keyW -> BUF2 ----
  #pragma unroll
  for (int nt = 0; nt < 8; ++nt) {
    const int e = nt >> 1, d = (nt & 1) * 16 + lr;
    f32x4 acc = {0.f, 0.f, 0.f, 0.f};
    const u16* wr = g_wt + OFF_SEL + (nt * 16 + lr) * 128 + lg * 8;
    #pragma unroll
    for (int ks = 0; ks < 4; ++ks)
      acc = __builtin_amdgcn_mfma_f32_16x16x32_bf16(sefr[ks], ld8(wr + ks * 32), acc, 0, 0, 0);
    #pragma unroll
    for (int r = 0; r < 4; ++r)
      lds[BUF1 + ((e * 8 + a) * 16 + 4 * lg + r) * 40 + d] = f2b(acc[r]);
  }
  #pragma unroll
  for (int nt = 0; nt < 8; ++nt) {
    const int e = nt >> 1, d = (nt & 1) * 16 + lr;
    f32x4 acc = {0.f, 0.f, 0.f, 0.f};
    const u16* wr = g_wt + OFF_KEY + (nt * 16 + lr) * 128 + lg * 8;
    #pragma unroll
    for (int ks = 0; ks < 4; ++ks)
      acc = __builtin_amdgcn_mfma_f32_16x16x32_bf16(safr[ks], ld8(wr + ks * 32), acc, 0, 0, 0);
    #pragma unroll
    for (int r = 0; r < 4; ++r)
      lds[BUF2 + ((e * 8 + a) * 16 + 4 * lg + r) * 40 + d] = f2b(acc[r]);
  }
  __syncthreads();

  // ---- P5: logits + masked softmax (thread = (e,i,t)) -> W [e][i][t][8j] bf16 ----
  {
    const int e = tid >> 7, i = (tid >> 4) & 7, t = tid & 15;
    float selv[32];
    #pragma unroll
    for (int q = 0; q < 4; ++q) {
      short8 s = ld8(&lds[BUF1 + ((e * 8 + i) * 16 + t) * 40 + q * 8]);
      #pragma unroll
      for (int z = 0; z < 8; ++z) selv[q * 8 + z] = b2f((u16)s[z]);
    }
    float lgt[8];
    #pragma unroll
    for (int j = 0; j < 8; ++j) {
      float acc = 0.f;
      #pragma unroll
      for (int q = 0; q < 4; ++q) {
        short8 k8 = ld8(&lds[BUF2 + ((e * 8 + j) * 16 + t) * 40 + q * 8]);
        #pragma unroll
        for (int z = 0; z < 8; ++z) acc = fmaf(selv[q * 8 + z], b2f((u16)k8[z]), acc);
      }
      lgt[j] = (j == i) ? -1e9f : acc * 0.17677669529663687f;  // 1/sqrt(32), self-mask
    }
    float m = lgt[0];
    #pragma unroll
    for (int j = 1; j < 8; ++j) m = fmaxf(m, lgt[j]);
    float s = 0.f;
    #pragma unroll
    for (int j = 0; j < 8; ++j) { lgt[j] = __expf(lgt[j] - m); s += lgt[j]; }
    float inv = 1.f / s;
    short8 w8;
    #pragma unroll
    for (int j = 0; j < 8; ++j) w8[j] = (short)f2b(lgt[j] * inv);
    *reinterpret_cast<short8*>(&lds[SW + ((e * 8 + i) * 16 + t) * 8]) = w8;
  }
  __syncthreads();

  // ---- P6: vals = lrelu(sa @ valW + valb) -> BUF1 (sel dead) ----
  #pragma unroll
  for (int nt = 0; nt < 8; ++nt) {
    const int e = nt >> 1, d = (nt & 1) * 16 + lr;
    f32x4 acc = {0.f, 0.f, 0.f, 0.f};
    const u16* wr = g_wt + OFF_VAL + (nt * 16 + lr) * 128 + lg * 8;
    #pragma unroll
    for (int ks = 0; ks < 4; ++ks)
      acc = __builtin_amdgcn_mfma_f32_16x16x32_bf16(safr[ks], ld8(wr + ks * 32), acc, 0, 0, 0);
    float bias = g_valb[nt * 16 + lr];
    #pragma unroll
    for (int r = 0; r < 4; ++r)
      lds[BUF1 + ((e * 8 + a) * 16 + 4 * lg + r) * 40 + d] = f2b(lrelu(acc[r] + bias));
  }
  __syncthreads();

  // ---- P7: other = w @ vals (thread = (e,i,t)) -> BUF2 as [a][t][136] (keys dead) ----
  {
    const int e = tid >> 7, i = (tid >> 4) & 7, t = tid & 15;
    float ov[32];
    #pragma unroll
    for (int d = 0; d < 32; ++d) ov[d] = 0.f;
    short8 wv = ld8(&lds[SW + ((e * 8 + i) * 16 + t) * 8]);
    #pragma unroll
    for (int j = 0; j < 8; ++j) {
      float wj = b2f((u16)wv[j]);
      #pragma unroll
      for (int q = 0; q < 4; ++q) {
        short8 v = ld8(&lds[BUF1 + ((e * 8 + j) * 16 + t) * 40 + q * 8]);
        #pragma unroll
        for (int z = 0; z < 8; ++z) ov[q * 8 + z] = fmaf(wj, b2f((u16)v[z]), ov[q * 8 + z]);
      }
    }
    #pragma unroll
    for (int q = 0; q < 4; ++q) {
      short8 s;
      #pragma unroll
      for (int z = 0; z < 8; ++z) s[z] = (short)f2b(ov[q * 8 + z]);
      *reinterpret_cast<short8*>(&lds[BUF2 + (i * 16 + t) * 136 + e * 32 + q * 8]) = s;
    }
  }
  __syncthreads();

  // ---- P8: h1 = lrelu([se|other] @ cW1 + cb1) -> SA (sa dead) ----
  {
    short8 cf[8];
    #pragma unroll
    for (int ks = 0; ks < 4; ++ks) {
      cf[ks] = sefr[ks];
      cf[4 + ks] = ld8(&lds[BUF2 + (a * 16 + lr) * 136 + ks * 32 + lg * 8]);
    }
    const u16* wb = g_wt + OFF_C1 + a * 32768 + lr * 256 + lg * 8;
    #pragma unroll
    for (int nt = 0; nt < 8; ++nt) {
      f32x4 acc = {0.f, 0.f, 0.f, 0.f};
      const u16* wr = wb + nt * (16 * 256);
      #pragma unroll
      for (int ks = 0; ks < 8; ++ks)
        acc = __builtin_amdgcn_mfma_f32_16x16x32_bf16(cf[ks], ld8(wr + ks * 32), acc, 0, 0, 0);
      float bias = g_cb1[a * NH + nt * 16 + lr];
      #pragma unroll
      for (int r = 0; r < 4; ++r)
        lds[SA + (a * 16 + 4 * lg + r) * 136 + nt * 16 + lr] = f2b(lrelu(acc[r] + bias));
    }
  }
  __syncthreads();

  // ---- P9: all_q = h1 @ cW2 + cb2 ; pick idx ----
  {
    f32x4 acc = {0.f, 0.f, 0.f, 0.f};
    const u16* wr = g_wt + OFF_C2 + a * 2048 + lr * 128 + lg * 8;
    #pragma unroll
    for (int ks = 0; ks < 4; ++ks) {
      short8 h = ld8(&lds[SA + (a * 16 + lr) * 136 + ks * 32 + lg * 8]);
      acc = __builtin_amdgcn_mfma_f32_16x16x32_bf16(h, ld8(wr + ks * 32), acc, 0, 0, 0);
    }
    float bias = g_cb2[a * NACT + lr];  // col o = lr
    #pragma unroll
    for (int r = 0; r < 4; ++r) {
      int t = 4 * lg + r;
      if ((int)lr == s_idx[a * 16 + t])
        g_out[(size_t)a * BT + g0 + t] = acc[r] + bias;
    }
  }
}

extern "C" void kernel_launch(void* const* d_in, const int* in_sizes, int n_in,
                              void* d_out, int out_size, void* d_ws, size_t ws_size,
                              hipStream_t stream) {
  (void)in_sizes; (void)n_in; (void)d_ws; (void)ws_size; (void)out_size;
  const float* obs  = (const float*)d_in[0];
  const float* u    = (const float*)d_in[1];
  const float* encW = (const float*)d_in[2];
  const float* encb = (const float*)d_in[3];
  const float* sW   = (const float*)d_in[4];
  const float* sb   = (const float*)d_in[5];
  const float* keyW = (const float*)d_in[6];
  const float* selW = (const float*)d_in[7];
  const float* valW = (const float*)d_in[8];
  const float* valb = (const float*)d_in[9];
  const float* cW1  = (const float*)d_in[10];
  const float* cb1  = (const float*)d_in[11];
  const float* cW2  = (const float*)d_in[12];
  const float* cb2  = (const float*)d_in[13];

  hipLaunchKernelGGL(maac_wt, dim3(1920), dim3(256), 0, stream,
                     encW, sW, keyW, selW, valW, cW1, cW2);
  hipLaunchKernelGGL(maac_main, dim3(BT / TOK), dim3(NTHREADS), 0, stream,
                     obs, u, encb, sb, valb, cb1, cb2, (float*)d_out);
}

// Round 4
// 381.174 us; speedup vs baseline: 3.0121x; 1.0725x over previous
//
#include <hip/hip_runtime.h>

namespace {
constexpr int NA = 8, BT = 32768, NOBS = 64, NACT = 16, NH = 128;
constexpr int TOK = 16, NTHREADS = 512;
// g_wt table offsets (u16 units)
constexpr int OFF_ENC = 0;        // [8][128n][96k] (k>=80 zero)
constexpr int OFF_S   = 98304;    // [8][128n][64k]
constexpr int OFF_KEY = 163840;   // [128n][128k]  n = e*32+d
constexpr int OFF_SEL = 180224;   // [128n][128k]
constexpr int OFF_VAL = 196608;   // [128n][128k]
constexpr int OFF_C1  = 212992;   // [8][128n][256k]
constexpr int OFF_C2  = 475136;   // [8][16n][128k]
constexpr int WT_TOTAL = 491520;
}

typedef short short8 __attribute__((ext_vector_type(8)));
typedef float f32x4 __attribute__((ext_vector_type(4)));
typedef unsigned short u16;

__device__ u16 g_wt[WT_TOTAL];

__device__ __forceinline__ u16 f2b(float x) {  // RNE f32->bf16
  unsigned b = __float_as_uint(x);
  return (u16)((b + 0x7FFFu + ((b >> 16) & 1u)) >> 16);
}
__device__ __forceinline__ float b2f(u16 h) { return __uint_as_float(((unsigned)h) << 16); }
__device__ __forceinline__ float lrelu(float x) { return x > 0.0f ? x : 0.01f * x; }
__device__ __forceinline__ short8 ld8(const u16* p) { return *reinterpret_cast<const short8*>(p); }
__device__ __forceinline__ short8 pk8(float4 p, float4 q) {
  short8 r;
  r[0] = (short)f2b(p.x); r[1] = (short)f2b(p.y); r[2] = (short)f2b(p.z); r[3] = (short)f2b(p.w);
  r[4] = (short)f2b(q.x); r[5] = (short)f2b(q.y); r[6] = (short)f2b(q.z); r[7] = (short)f2b(q.w);
  return r;
}

// ---------------- Prologue: transpose+cvt all weights into g_wt ----------------
__global__ void maac_wt(const float* __restrict__ encW, const float* __restrict__ sW,
                        const float* __restrict__ keyW, const float* __restrict__ selW,
                        const float* __restrict__ valW, const float* __restrict__ cW1,
                        const float* __restrict__ cW2) {
  for (int i = blockIdx.x * blockDim.x + threadIdx.x; i < WT_TOTAL; i += gridDim.x * blockDim.x) {
    float v; int o = i;
    if (o < OFF_S) {                // enc: [a][n][96] <- encW[a][k][n], zero k>=80
      int a = o / 12288, r = o % 12288, n = r / 96, k = r % 96;
      v = (k < 80) ? encW[a * 10240 + k * 128 + n] : 0.0f;
    } else if (o < OFF_KEY) {       // s: [a][n][64]
      int q = o - OFF_S; int a = q / 8192, r = q % 8192, n = r / 64, k = r % 64;
      v = sW[a * 8192 + k * 128 + n];
    } else if (o < OFF_SEL) {       // key: [n=e*32+d][k=h]
      int q = o - OFF_KEY; int n = q / 128, k = q % 128;
      v = keyW[(n >> 5) * 4096 + k * 32 + (n & 31)];
    } else if (o < OFF_VAL) {
      int q = o - OFF_SEL; int n = q / 128, k = q % 128;
      v = selW[(n >> 5) * 4096 + k * 32 + (n & 31)];
    } else if (o < OFF_C1) {
      int q = o - OFF_VAL; int n = q / 128, k = q % 128;
      v = valW[(n >> 5) * 4096 + k * 32 + (n & 31)];
    } else if (o < OFF_C2) {        // c1: [a][n][256]
      int q = o - OFF_C1; int a = q / 32768, r = q % 32768, n = r / 256, k = r % 256;
      v = cW1[a * 32768 + k * 128 + n];
    } else {                        // c2: [a][n=o][128]
      int q = o - OFF_C2; int a = q / 2048, r = q % 2048, n = r / 128, k = r % 128;
      v = cW2[a * 2048 + k * 16 + n];
    }
    g_wt[i] = f2b(v);
  }
}

// ---------------- Main fused kernel: 16 tokens x 8 agents per block ----------------
// LDS (u16): KOFF keys[4e][8a][16t][32d] =16384 (later: other[8a][16t][128h] XOR-swz)
//            SOFF sel  same               =16384 (later: vals)
//            SCR  wave-private roundtrip [8w][16][40] = 5120
// Total 37888 u16 = 75776 B (+512 idx) -> 2 blocks/CU.
__global__ __launch_bounds__(NTHREADS, 4) void maac_main(
    const float* __restrict__ g_obs, const float* __restrict__ g_u,
    const float* __restrict__ g_encb, const float* __restrict__ g_sb,
    const float* __restrict__ g_valb, const float* __restrict__ g_cb1,
    const float* __restrict__ g_cb2, float* __restrict__ g_out) {
  __shared__ __align__(16) u16 lds[37888];
  __shared__ int s_idx[128];
  constexpr int KOFF = 0, SOFF = 16384, SCR = 32768;

  const int tid = threadIdx.x;
  const int g0 = blockIdx.x * TOK;
  const int a = tid >> 6, l = tid & 63, lr = l & 15, lg = l >> 4;
  const int scrw = SCR + a * 640;   // 16 rows x 40 u16, wave-private

  // ---- P0: argmax(u) (first-max) ----
  if (tid < 128) {
    int aa = tid >> 4, t = tid & 15;
    const float* up = g_u + ((size_t)aa * BT + g0 + t) * NACT;
    int best = 0; float bv = up[0];
    #pragma unroll
    for (int o = 1; o < NACT; ++o) { float v = up[o]; if (v > bv) { bv = v; best = o; } }
    s_idx[tid] = best;
  }

  // ---- A-frags for enc/s_enc from global: row = token g0+lr, k = ks*32+lg*8+j ----
  short8 afr0, afr1, afr2;
  {
    const float4* o4 = reinterpret_cast<const float4*>(g_obs + ((size_t)a * BT + g0 + lr) * NOBS);
    afr0 = pk8(o4[lg * 2], o4[lg * 2 + 1]);
    afr1 = pk8(o4[8 + lg * 2], o4[8 + lg * 2 + 1]);
    if (lg < 2) {
      const float4* u4 = reinterpret_cast<const float4*>(g_u + ((size_t)a * BT + g0 + lr) * NACT);
      afr2 = pk8(u4[lg * 2], u4[lg * 2 + 1]);
    } else {
      afr2 = short8{0, 0, 0, 0, 0, 0, 0, 0};
    }
  }

  short8 safr[4], sefr[4];

  // ---- P1: sa = lrelu(inp @ encW + encb), granule round-trip -> safr ----
  {
    const u16* wb = g_wt + OFF_ENC + a * 12288 + lr * 96 + lg * 8;
    #pragma unroll
    for (int g = 0; g < 4; ++g) {
      #pragma unroll
      for (int ntl = 0; ntl < 2; ++ntl) {
        const int nt = 2 * g + ntl;
        f32x4 acc = {0.f, 0.f, 0.f, 0.f};
        const u16* wr = wb + nt * (16 * 96);
        acc = __builtin_amdgcn_mfma_f32_16x16x32_bf16(afr0, ld8(wr), acc, 0, 0, 0);
        acc = __builtin_amdgcn_mfma_f32_16x16x32_bf16(afr1, ld8(wr + 32), acc, 0, 0, 0);
        acc = __builtin_amdgcn_mfma_f32_16x16x32_bf16(afr2, ld8(wr + 64), acc, 0, 0, 0);
        float bias = g_encb[a * NH + nt * 16 + lr];
        #pragma unroll
        for (int r = 0; r < 4; ++r)
          lds[scrw + (4 * lg + r) * 40 + ntl * 16 + lr] = f2b(lrelu(acc[r] + bias));
      }
      safr[g] = ld8(&lds[scrw + lr * 40 + lg * 8]);   // wave-private, DS-ordered: no barrier
    }
  }
  // ---- P2: se = lrelu(obs @ sW + sb), granule round-trip -> sefr ----
  {
    const u16* wb = g_wt + OFF_S + a * 8192 + lr * 64 + lg * 8;
    #pragma unroll
    for (int g = 0; g < 4; ++g) {
      #pragma unroll
      for (int ntl = 0; ntl < 2; ++ntl) {
        const int nt = 2 * g + ntl;
        f32x4 acc = {0.f, 0.f, 0.f, 0.f};
        const u16* wr = wb + nt * (16 * 64);
        acc = __builtin_amdgcn_mfma_f32_16x16x32_bf16(afr0, ld8(wr), acc, 0, 0, 0);
        acc = __builtin_amdgcn_mfma_f32_16x16x32_bf16(afr1, ld8(wr + 32), acc, 0, 0, 0);
        float bias = g_sb[a * NH + nt * 16 + lr];
        #pragma unroll
        for (int r = 0; r < 4; ++r)
          lds[scrw + (4 * lg + r) * 40 + ntl * 16 + lr] = f2b(lrelu(acc[r] + bias));
      }
      sefr[g] = ld8(&lds[scrw + lr * 40 + lg * 8]);
    }
  }

  // ---- P3: keys = sa@keyW -> KOFF ; sel = se@selW -> SOFF (interleaved chains) ----
  #pragma unroll
  for (int nt = 0; nt < 8; ++nt) {
    const int e = nt >> 1, d = (nt & 1) * 16 + lr;
    const u16* wk = g_wt + OFF_KEY + (nt * 16 + lr) * 128 + lg * 8;
    const u16* ws = g_wt + OFF_SEL + (nt * 16 + lr) * 128 + lg * 8;
    f32x4 ak = {0.f, 0.f, 0.f, 0.f}, as_ = {0.f, 0.f, 0.f, 0.f};
    #pragma unroll
    for (int ks = 0; ks < 4; ++ks) {
      ak  = __builtin_amdgcn_mfma_f32_16x16x32_bf16(safr[ks], ld8(wk + ks * 32), ak, 0, 0, 0);
      as_ = __builtin_amdgcn_mfma_f32_16x16x32_bf16(sefr[ks], ld8(ws + ks * 32), as_, 0, 0, 0);
    }
    #pragma unroll
    for (int r = 0; r < 4; ++r) {
      lds[KOFF + ((e * 8 + a) * 16 + 4 * lg + r) * 32 + d] = f2b(ak[r]);
      lds[SOFF + ((e * 8 + a) * 16 + 4 * lg + r) * 32 + d] = f2b(as_[r]);
    }
  }
  __syncthreads();   // B1: keys+sel (+idx) visible

  // ---- P5: logits + masked softmax (thread = (e,i,t)), w kept in REGISTERS ----
  float w[NA];
  {
    const int e = tid >> 7, i = (tid >> 4) & 7, t = tid & 15;
    float selv[32];
    #pragma unroll
    for (int q = 0; q < 4; ++q) {
      short8 s = ld8(&lds[SOFF + ((e * 8 + i) * 16 + t) * 32 + q * 8]);
      #pragma unroll
      for (int z = 0; z < 8; ++z) selv[q * 8 + z] = b2f((u16)s[z]);
    }
    float lgt[NA];
    #pragma unroll
    for (int j = 0; j < NA; ++j) {
      float acc = 0.f;
      #pragma unroll
      for (int q = 0; q < 4; ++q) {
        short8 k8 = ld8(&lds[KOFF + ((e * 8 + j) * 16 + t) * 32 + q * 8]);
        #pragma unroll
        for (int z = 0; z < 8; ++z) acc = fmaf(selv[q * 8 + z], b2f((u16)k8[z]), acc);
      }
      lgt[j] = (j == i) ? -1e9f : acc * 0.17677669529663687f;  // 1/sqrt(32), self-mask
    }
    float m = lgt[0];
    #pragma unroll
    for (int j = 1; j < NA; ++j) m = fmaxf(m, lgt[j]);
    float s = 0.f;
    #pragma unroll
    for (int j = 0; j < NA; ++j) { lgt[j] = __expf(lgt[j] - m); s += lgt[j]; }
    float inv = 1.f / s;
    #pragma unroll
    for (int j = 0; j < NA; ++j) w[j] = lgt[j] * inv;
  }
  __syncthreads();   // B2: all keys/sel reads done

  // ---- P6: vals = lrelu(sa @ valW + valb) -> SOFF (sel dead) ----
  #pragma unroll
  for (int nt = 0; nt < 8; ++nt) {
    const int e = nt >> 1, d = (nt & 1) * 16 + lr;
    f32x4 acc = {0.f, 0.f, 0.f, 0.f};
    const u16* wr = g_wt + OFF_VAL + (nt * 16 + lr) * 128 + lg * 8;
    #pragma unroll
    for (int ks = 0; ks < 4; ++ks)
      acc = __builtin_amdgcn_mfma_f32_16x16x32_bf16(safr[ks], ld8(wr + ks * 32), acc, 0, 0, 0);
    float bias = g_valb[nt * 16 + lr];
    #pragma unroll
    for (int r = 0; r < 4; ++r)
      lds[SOFF + ((e * 8 + a) * 16 + 4 * lg + r) * 32 + d] = f2b(lrelu(acc[r] + bias));
  }
  __syncthreads();   // B3: vals visible

  // ---- P7: other = w @ vals -> KOFF as [i][t][128] with XOR swizzle (keys dead) ----
  {
    const int e = tid >> 7, i = (tid >> 4) & 7, t = tid & 15;
    float ov[32];
    #pragma unroll
    for (int d = 0; d < 32; ++d) ov[d] = 0.f;
    #pragma unroll
    for (int j = 0; j < NA; ++j) {
      float wj = w[j];
      #pragma unroll
      for (int q = 0; q < 4; ++q) {
        short8 v = ld8(&lds[SOFF + ((e * 8 + j) * 16 + t) * 32 + q * 8]);
        #pragma unroll
        for (int z = 0; z < 8; ++z) ov[q * 8 + z] = fmaf(wj, b2f((u16)v[z]), ov[q * 8 + z]);
      }
    }
    #pragma unroll
    for (int q = 0; q < 4; ++q) {
      short8 s;
      #pragma unroll
      for (int z = 0; z < 8; ++z) s[z] = (short)f2b(ov[q * 8 + z]);
      *reinterpret_cast<short8*>(
          &lds[KOFF + (i * 16 + t) * 128 + ((e * 32 + q * 8) ^ ((t & 7) * 8))]) = s;
    }
  }
  __syncthreads();   // B4: other visible

  // ---- P8: h1 = lrelu([se|other] @ cW1 + cb1), granule round-trip -> h1fr ----
  short8 h1fr[4];
  {
    short8 cf[8];
    #pragma unroll
    for (int ks = 0; ks < 4; ++ks) {
      cf[ks] = sefr[ks];
      cf[4 + ks] = ld8(&lds[KOFF + (a * 16 + lr) * 128 + ((ks * 32 + lg * 8) ^ ((lr & 7) * 8))]);
    }
    const u16* wb = g_wt + OFF_C1 + a * 32768 + lr * 256 + lg * 8;
    #pragma unroll
    for (int g = 0; g < 4; ++g) {
      #pragma unroll
      for (int ntl = 0; ntl < 2; ++ntl) {
        const int nt = 2 * g + ntl;
        f32x4 acc = {0.f, 0.f, 0.f, 0.f};
        const u16* wr = wb + nt * (16 * 256);
        #pragma unroll
        for (int ks = 0; ks < 8; ++ks)
          acc = __builtin_amdgcn_mfma_f32_16x16x32_bf16(cf[ks], ld8(wr + ks * 32), acc, 0, 0, 0);
        float bias = g_cb1[a * NH + nt * 16 + lr];
        #pragma unroll
        for (int r = 0; r < 4; ++r)
          lds[scrw + (4 * lg + r) * 40 + ntl * 16 + lr] = f2b(lrelu(acc[r] + bias));
      }
      h1fr[g] = ld8(&lds[scrw + lr * 40 + lg * 8]);   // wave-private
    }
  }

  // ---- P9: all_q = h1 @ cW2 + cb2 ; pick idx ----
  {
    f32x4 acc = {0.f, 0.f, 0.f, 0.f};
    const u16* wr = g_wt + OFF_C2 + a * 2048 + lr * 128 + lg * 8;
    #pragma unroll
    for (int ks = 0; ks < 4; ++ks)
      acc = __builtin_amdgcn_mfma_f32_16x16x32_bf16(h1fr[ks], ld8(wr + ks * 32), acc, 0, 0, 0);
    float bias = g_cb2[a * NACT + lr];  // col o = lr
    #pragma unroll
    for (int r = 0; r < 4; ++r) {
      int t = 4 * lg + r;
      if ((int)lr == s_idx[a * 16 + t])
        g_out[(size_t)a * BT + g0 + t] = acc[r] + bias;
    }
  }
}

extern "C" void kernel_launch(void* const* d_in, const int* in_sizes, int n_in,
                              void* d_out, int out_size, void* d_ws, size_t ws_size,
                              hipStream_t stream) {
  (void)in_sizes; (void)n_in; (void)d_ws; (void)ws_size; (void)out_size;
  const float* obs  = (const float*)d_in[0];
  const float* u    = (const float*)d_in[1];
  const float* encW = (const float*)d_in[2];
  const float* encb = (const float*)d_in[3];
  const float* sW   = (const float*)d_in[4];
  const float* sb   = (const float*)d_in[5];
  const float* keyW = (const float*)d_in[6];
  const float* selW = (const float*)d_in[7];
  const float* valW = (const float*)d_in[8];
  const float* valb = (const float*)d_in[9];
  const float* cW1  = (const float*)d_in[10];
  const float* cb1  = (const float*)d_in[11];
  const float* cW2  = (const float*)d_in[12];
  const float* cb2  = (const float*)d_in[13];

  hipLaunchKernelGGL(maac_wt, dim3(1920), dim3(256), 0, stream,
                     encW, sW, keyW, selW, valW, cW1, cW2);
  hipLaunchKernelGGL(maac_main, dim3(BT / TOK), dim3(NTHREADS), 0, stream,
                     obs, u, encb, sb, valb, cb1, cb2, (float*)d_out);
}